// Round 1
// baseline (666.244 us; speedup 1.0000x reference)
//
#include <hip/hip_runtime.h>
#include <hip/hip_bf16.h>

#define B_ROWS 4096
#define M_ROWS 65536
#define DIM 512
#define TOPK 8
#define CAP 512
#define TAU 0.132583f       // 3/sqrt(512): ~88 candidates/query expected
#define FB_N 2048           // fallback merge entries = 256 threads * 8

typedef unsigned short u16;
typedef unsigned short u16x8 __attribute__((ext_vector_type(8)));
typedef __bf16 bf16x8 __attribute__((ext_vector_type(8)));
typedef float f32x4 __attribute__((ext_vector_type(4)));

__device__ inline u16 f2bf(float x) {
  unsigned u = __builtin_bit_cast(unsigned, x);
  u = (u + 0x7fffu + ((u >> 16) & 1u)) >> 16;  // RNE, finite inputs only
  return (u16)u;
}

// ---- normalize rows -> bf16 (one wave per row) ----
__global__ __launch_bounds__(256) void norm_kernel(const float* __restrict__ in,
                                                   u16* __restrict__ out, int nrows) {
  int gw = (int)((blockIdx.x * 256 + threadIdx.x) >> 6);
  int lane = threadIdx.x & 63;
  if (gw >= nrows) return;
  const float4* r = (const float4*)(in + (size_t)gw * DIM);
  float4 v0 = r[lane * 2 + 0];
  float4 v1 = r[lane * 2 + 1];
  float ss = v0.x*v0.x + v0.y*v0.y + v0.z*v0.z + v0.w*v0.w
           + v1.x*v1.x + v1.y*v1.y + v1.z*v1.z + v1.w*v1.w;
#pragma unroll
  for (int off = 32; off > 0; off >>= 1) ss += __shfl_xor(ss, off);
  float inv = 1.0f / fmaxf(sqrtf(ss), 1e-8f);
  u16x8 o;
  o[0]=f2bf(v0.x*inv); o[1]=f2bf(v0.y*inv); o[2]=f2bf(v0.z*inv); o[3]=f2bf(v0.w*inv);
  o[4]=f2bf(v1.x*inv); o[5]=f2bf(v1.y*inv); o[6]=f2bf(v1.z*inv); o[7]=f2bf(v1.w*inv);
  *(u16x8*)(out + (size_t)gw * DIM + lane * 8) = o;
}

// ---- bf16 MFMA GEMM (128x128 tile, BK=32) + threshold candidate append ----
__global__ __launch_bounds__(256) void gemm_select(const u16* __restrict__ qn,
                                                   const u16* __restrict__ mn,
                                                   int* __restrict__ count,
                                                   int* __restrict__ cand) {
  __shared__ u16 lA[128 * 32];  // 8 KB, row-major [128][32]
  __shared__ u16 lB[128 * 32];
  int bid = blockIdx.x;
  int mtile = bid & 511;   // 512 m-tiles
  int qtile = bid >> 9;    // 32 q-tiles
  int tid = threadIdx.x;
  int lane = tid & 63;
  int w = tid >> 6;
  int wr = w >> 1, wc = w & 1;

  const u16* gA = qn + (size_t)qtile * 128 * DIM;
  const u16* gB = mn + (size_t)mtile * 128 * DIM;

  // staging: 512 chunks of 16B per tile; thread t handles chunks t and t+256
  int c0 = tid, c1 = tid + 256;
  int r0 = c0 >> 2, o0 = (c0 & 3) * 8;
  int r1 = c1 >> 2, o1 = (c1 & 3) * 8;

  f32x4 acc[4][4];
#pragma unroll
  for (int i = 0; i < 4; i++)
#pragma unroll
    for (int j = 0; j < 4; j++) {
      f32x4 z = {0.f, 0.f, 0.f, 0.f};
      acc[i][j] = z;
    }

  for (int k0 = 0; k0 < DIM; k0 += 32) {
    __syncthreads();  // protect previous iteration's LDS reads
    u16x8 ta0 = *(const u16x8*)(gA + (size_t)r0 * DIM + k0 + o0);
    u16x8 ta1 = *(const u16x8*)(gA + (size_t)r1 * DIM + k0 + o1);
    u16x8 tb0 = *(const u16x8*)(gB + (size_t)r0 * DIM + k0 + o0);
    u16x8 tb1 = *(const u16x8*)(gB + (size_t)r1 * DIM + k0 + o1);
    *(u16x8*)&lA[c0 * 8] = ta0;
    *(u16x8*)&lA[c1 * 8] = ta1;
    *(u16x8*)&lB[c0 * 8] = tb0;
    *(u16x8*)&lB[c1 * 8] = tb1;
    __syncthreads();

    int rlo = lane & 15;
    int ks = (lane >> 4) * 8;
    bf16x8 af[4], bfr[4];
#pragma unroll
    for (int mi = 0; mi < 4; mi++)
      af[mi] = __builtin_bit_cast(bf16x8, *(const u16x8*)&lA[(wr*64 + mi*16 + rlo)*32 + ks]);
#pragma unroll
    for (int ni = 0; ni < 4; ni++)
      bfr[ni] = __builtin_bit_cast(bf16x8, *(const u16x8*)&lB[(wc*64 + ni*16 + rlo)*32 + ks]);
#pragma unroll
    for (int mi = 0; mi < 4; mi++)
#pragma unroll
      for (int ni = 0; ni < 4; ni++)
        acc[mi][ni] = __builtin_amdgcn_mfma_f32_16x16x32_bf16(af[mi], bfr[ni], acc[mi][ni], 0, 0, 0);
  }

  // epilogue: C row (query) = (lane>>4)*4 + reg, col (mem) = lane&15  [m89 layout]
  int qbase = qtile * 128 + wr * 64 + (lane >> 4) * 4;
  int mbase = mtile * 128 + wc * 64 + (lane & 15);
#pragma unroll
  for (int mi = 0; mi < 4; mi++)
#pragma unroll
    for (int ni = 0; ni < 4; ni++)
#pragma unroll
      for (int r = 0; r < 4; r++) {
        float v = acc[mi][ni][r];
        if (v > TAU) {
          int qq = qbase + mi * 16 + r;
          int mm = mbase + ni * 16;
          int pos = atomicAdd(&count[qq], 1);
          if (pos < CAP) cand[(size_t)qq * CAP + pos] = mm;
        }
      }
}

// ---- per-query: fp64 rescore of candidates, exact top-8, gather+mean ----
__global__ __launch_bounds__(256) void topk_kernel(const float* __restrict__ q,
                                                   const float* __restrict__ mem,
                                                   const int* __restrict__ count,
                                                   const int* __restrict__ cand,
                                                   float* __restrict__ out) {
  __shared__ double s_sims[FB_N];
  __shared__ int s_cidx[FB_N];
  __shared__ double s_red[4];
  __shared__ int s_redj[4];
  __shared__ int s_win[TOPK];

  int b = blockIdx.x;
  int tid = threadIdx.x;
  int lane = tid & 63;
  int w = tid >> 6;

  const float* qrow = q + (size_t)b * DIM;
  const float4* qv = (const float4*)qrow;
  float4 q0 = qv[lane * 2], q1 = qv[lane * 2 + 1];
  double q8[8] = {q0.x, q0.y, q0.z, q0.w, q1.x, q1.y, q1.z, q1.w};
  double qq = 0;
#pragma unroll
  for (int e = 0; e < 8; e++) qq += q8[e] * q8[e];
#pragma unroll
  for (int off = 32; off > 0; off >>= 1) qq += __shfl_xor(qq, off);
  double qnorm = fmax(sqrt(qq), 1e-8);

  int c = count[b];
  int n;
  if (c >= TOPK && c <= CAP) {
    // normal path: each wave rescores candidates j = w, w+4, ...
    for (int j = w; j < c; j += 4) {
      int mi = cand[(size_t)b * CAP + j];
      const float4* mv = (const float4*)(mem + (size_t)mi * DIM);
      float4 m0 = mv[lane * 2], m1 = mv[lane * 2 + 1];
      double m8[8] = {m0.x, m0.y, m0.z, m0.w, m1.x, m1.y, m1.z, m1.w};
      double dot = 0, mm = 0;
#pragma unroll
      for (int e = 0; e < 8; e++) { dot += q8[e] * m8[e]; mm += m8[e] * m8[e]; }
#pragma unroll
      for (int off = 32; off > 0; off >>= 1) {
        dot += __shfl_xor(dot, off);
        mm += __shfl_xor(mm, off);
      }
      if (lane == 0) {
        s_sims[j] = dot / (qnorm * fmax(sqrt(mm), 1e-8));
        s_cidx[j] = mi;
      }
    }
    n = c;
  } else {
    // fallback (cold, correctness-only): full scan, per-thread top-8, block merge
    double tv[8]; int tix[8];
#pragma unroll
    for (int r = 0; r < 8; r++) { tv[r] = -1e300; tix[r] = -1; }
    for (int row = tid; row < M_ROWS; row += 256) {
      const float4* mv = (const float4*)(mem + (size_t)row * DIM);
      double dot = 0, mm = 0;
      for (int e = 0; e < DIM / 4; e++) {
        float4 m4 = mv[e], qk = qv[e];
        dot += (double)m4.x * qk.x + (double)m4.y * qk.y + (double)m4.z * qk.z + (double)m4.w * qk.w;
        mm  += (double)m4.x * m4.x + (double)m4.y * m4.y + (double)m4.z * m4.z + (double)m4.w * m4.w;
      }
      double sim = dot / (qnorm * fmax(sqrt(mm), 1e-8));
      int am = 0;
#pragma unroll
      for (int r = 1; r < 8; r++) if (tv[r] < tv[am]) am = r;
      if (sim > tv[am]) { tv[am] = sim; tix[am] = row; }
    }
#pragma unroll
    for (int r = 0; r < 8; r++) { s_sims[tid * 8 + r] = tv[r]; s_cidx[tid * 8 + r] = tix[r]; }
    n = FB_N;
  }
  __syncthreads();

  // 8 rounds of block-wide argmax
  for (int r = 0; r < TOPK; r++) {
    double best = -1e300; int bj = -1;
    for (int j = tid; j < n; j += 256) {
      double v = s_sims[j];
      if (v > best) { best = v; bj = j; }
    }
#pragma unroll
    for (int off = 32; off > 0; off >>= 1) {
      double ov = __shfl_down(best, off);
      int oj = __shfl_down(bj, off);
      if (ov > best) { best = ov; bj = oj; }
    }
    if (lane == 0) { s_red[w] = best; s_redj[w] = bj; }
    __syncthreads();
    if (tid == 0) {
      double bb = s_red[0]; int jj = s_redj[0];
      for (int i = 1; i < 4; i++) if (s_red[i] > bb) { bb = s_red[i]; jj = s_redj[i]; }
      s_win[r] = s_cidx[jj];
      s_sims[jj] = -1e300;
    }
    __syncthreads();
  }

  // gather 8 winner rows, mean, write fp32 output
  float ax = 0.f, ay = 0.f;
#pragma unroll
  for (int r = 0; r < TOPK; r++) {
    const float2 v = *(const float2*)(mem + (size_t)s_win[r] * DIM + tid * 2);
    ax += v.x; ay += v.y;
  }
  float2 o; o.x = ax * 0.125f; o.y = ay * 0.125f;
  *(float2*)(out + (size_t)b * DIM + tid * 2) = o;
}

extern "C" void kernel_launch(void* const* d_in, const int* in_sizes, int n_in,
                              void* d_out, int out_size, void* d_ws, size_t ws_size,
                              hipStream_t stream) {
  (void)in_sizes; (void)n_in; (void)out_size; (void)ws_size;
  const float* q = (const float*)d_in[0];
  const float* mem = (const float*)d_in[1];
  float* out = (float*)d_out;

  char* ws = (char*)d_ws;
  u16* mn = (u16*)ws;                                        // 64 MB
  u16* qn = (u16*)(ws + (size_t)M_ROWS * DIM * 2);           // 4 MB
  int* count = (int*)(ws + (size_t)M_ROWS * DIM * 2 + (size_t)B_ROWS * DIM * 2);  // 16 KB
  int* cand = (int*)((char*)count + (size_t)B_ROWS * sizeof(int));                // 8 MB

  hipMemsetAsync(count, 0, B_ROWS * sizeof(int), stream);
  norm_kernel<<<M_ROWS / 4, 256, 0, stream>>>(mem, mn, M_ROWS);
  norm_kernel<<<B_ROWS / 4, 256, 0, stream>>>(q, qn, B_ROWS);
  gemm_select<<<(M_ROWS / 128) * (B_ROWS / 128), 256, 0, stream>>>(qn, mn, count, cand);
  topk_kernel<<<B_ROWS, 256, 0, stream>>>(q, mem, count, cand, out);
}

// Round 2
// 548.163 us; speedup vs baseline: 1.2154x; 1.2154x over previous
//
#include <hip/hip_runtime.h>
#include <hip/hip_bf16.h>

#define B_ROWS 4096
#define M_ROWS 65536
#define DIM 512
#define TOPK 8
#define CAP 512
#define TAU 0.132583f       // 3/sqrt(512): ~88 candidates/query expected
#define FB_N 2048           // fallback merge entries = 256 threads * 8

typedef unsigned short u16;
typedef unsigned int u32;
typedef unsigned short u16x8 __attribute__((ext_vector_type(8)));
typedef __bf16 bf16x8 __attribute__((ext_vector_type(8)));
typedef float f32x4 __attribute__((ext_vector_type(4)));

__device__ inline u16 f2bf(float x) {
  unsigned u = __builtin_bit_cast(unsigned, x);
  u = (u + 0x7fffu + ((u >> 16) & 1u)) >> 16;  // RNE, finite inputs only
  return (u16)u;
}

// async global->LDS, 16B per lane; LDS dest = wave-uniform base + lane*16
__device__ inline void gl_lds16(const u16* g, u16* l) {
  __builtin_amdgcn_global_load_lds(
      (const __attribute__((address_space(1))) u32*)g,
      (__attribute__((address_space(3))) u32*)l, 16, 0, 0);
}

// ---- normalize rows -> bf16 (one wave per row) ----
__global__ __launch_bounds__(256) void norm_kernel(const float* __restrict__ in,
                                                   u16* __restrict__ out, int nrows) {
  int gw = (int)((blockIdx.x * 256 + threadIdx.x) >> 6);
  int lane = threadIdx.x & 63;
  if (gw >= nrows) return;
  const float4* r = (const float4*)(in + (size_t)gw * DIM);
  float4 v0 = r[lane * 2 + 0];
  float4 v1 = r[lane * 2 + 1];
  float ss = v0.x*v0.x + v0.y*v0.y + v0.z*v0.z + v0.w*v0.w
           + v1.x*v1.x + v1.y*v1.y + v1.z*v1.z + v1.w*v1.w;
#pragma unroll
  for (int off = 32; off > 0; off >>= 1) ss += __shfl_xor(ss, off);
  float inv = 1.0f / fmaxf(sqrtf(ss), 1e-8f);
  u16x8 o;
  o[0]=f2bf(v0.x*inv); o[1]=f2bf(v0.y*inv); o[2]=f2bf(v0.z*inv); o[3]=f2bf(v0.w*inv);
  o[4]=f2bf(v1.x*inv); o[5]=f2bf(v1.y*inv); o[6]=f2bf(v1.z*inv); o[7]=f2bf(v1.w*inv);
  *(u16x8*)(out + (size_t)gw * DIM + lane * 8) = o;
}

// ---- bf16 MFMA GEMM (128x128 tile, BK=32, global_load_lds staging)
//      + threshold candidate append ----
__global__ __launch_bounds__(256) void gemm_select(const u16* __restrict__ qn,
                                                   const u16* __restrict__ mn,
                                                   int* __restrict__ count,
                                                   int* __restrict__ cand) {
  __shared__ u16 lA[128 * 32];  // 8 KB, row-major [128][32]
  __shared__ u16 lB[128 * 32];
  int bid = blockIdx.x;
  // concurrent blocks share the mn tile; qn (4MB) L2-resident per XCD
  int qtile = bid & 31;    // 32 q-tiles
  int mtile = bid >> 5;    // 512 m-tiles
  int tid = threadIdx.x;
  int lane = tid & 63;
  int w = tid >> 6;
  int wr = w >> 1, wc = w & 1;

  const u16* gA = qn + (size_t)qtile * 128 * DIM;
  const u16* gB = mn + (size_t)mtile * 128 * DIM;

  // staging geometry: wave w stages rows [w*32, w*32+32) of A and B,
  // two issues of 16 rows each; lane -> (row = base + lane>>2, chunk = lane&3)
  int srow = lane >> 2;        // 0..15
  int schk = (lane & 3) * 8;   // element offset of 16B chunk in row
  size_t gs0 = (size_t)(w * 32 + srow) * DIM + schk;        // issue 0
  size_t gs1 = (size_t)(w * 32 + 16 + srow) * DIM + schk;   // issue 1
  u16* lA0 = &lA[(w * 32) * 32];
  u16* lA1 = &lA[(w * 32 + 16) * 32];
  u16* lB0 = &lB[(w * 32) * 32];
  u16* lB1 = &lB[(w * 32 + 16) * 32];

  f32x4 acc[4][4];
#pragma unroll
  for (int i = 0; i < 4; i++)
#pragma unroll
    for (int j = 0; j < 4; j++) {
      f32x4 z = {0.f, 0.f, 0.f, 0.f};
      acc[i][j] = z;
    }

  int rlo = lane & 15;
  int ks = (lane >> 4) * 8;

  for (int k0 = 0; k0 < DIM; k0 += 32) {
    __syncthreads();  // previous iteration's LDS reads complete
    gl_lds16(gA + gs0 + k0, lA0);
    gl_lds16(gA + gs1 + k0, lA1);
    gl_lds16(gB + gs0 + k0, lB0);
    gl_lds16(gB + gs1 + k0, lB1);
    __syncthreads();  // compiler drains vmcnt(0) before s_barrier -> tiles ready

    bf16x8 af[4], bfr[4];
#pragma unroll
    for (int mi = 0; mi < 4; mi++)
      af[mi] = __builtin_bit_cast(bf16x8, *(const u16x8*)&lA[(wr*64 + mi*16 + rlo)*32 + ks]);
#pragma unroll
    for (int ni = 0; ni < 4; ni++)
      bfr[ni] = __builtin_bit_cast(bf16x8, *(const u16x8*)&lB[(wc*64 + ni*16 + rlo)*32 + ks]);
#pragma unroll
    for (int mi = 0; mi < 4; mi++)
#pragma unroll
      for (int ni = 0; ni < 4; ni++)
        acc[mi][ni] = __builtin_amdgcn_mfma_f32_16x16x32_bf16(af[mi], bfr[ni], acc[mi][ni], 0, 0, 0);
  }

  // epilogue: C row (query) = (lane>>4)*4 + reg, col (mem) = lane&15  [m89 layout]
  int qbase = qtile * 128 + wr * 64 + (lane >> 4) * 4;
  int mbase = mtile * 128 + wc * 64 + (lane & 15);
#pragma unroll
  for (int mi = 0; mi < 4; mi++)
#pragma unroll
    for (int ni = 0; ni < 4; ni++)
#pragma unroll
      for (int r = 0; r < 4; r++) {
        float v = acc[mi][ni][r];
        if (v > TAU) {
          int qq = qbase + mi * 16 + r;
          int mm = mbase + ni * 16;
          int pos = atomicAdd(&count[qq], 1);
          if (pos < CAP) cand[(size_t)qq * CAP + pos] = mm;
        }
      }
}

// ---- per-query: fp64 rescore of candidates, exact top-8, gather+mean ----
__global__ __launch_bounds__(256) void topk_kernel(const float* __restrict__ q,
                                                   const float* __restrict__ mem,
                                                   const int* __restrict__ count,
                                                   const int* __restrict__ cand,
                                                   float* __restrict__ out) {
  __shared__ double s_sims[FB_N];
  __shared__ int s_cidx[FB_N];
  __shared__ double s_red[4];
  __shared__ int s_redj[4];
  __shared__ int s_win[TOPK];

  int b = blockIdx.x;
  int tid = threadIdx.x;
  int lane = tid & 63;
  int w = tid >> 6;

  const float* qrow = q + (size_t)b * DIM;
  const float4* qv = (const float4*)qrow;
  float4 q0 = qv[lane * 2], q1 = qv[lane * 2 + 1];
  double q8[8] = {q0.x, q0.y, q0.z, q0.w, q1.x, q1.y, q1.z, q1.w};
  double qq = 0;
#pragma unroll
  for (int e = 0; e < 8; e++) qq += q8[e] * q8[e];
#pragma unroll
  for (int off = 32; off > 0; off >>= 1) qq += __shfl_xor(qq, off);
  double qnorm = fmax(sqrt(qq), 1e-8);

  int c = count[b];
  int n;
  if (c >= TOPK && c <= CAP) {
    // normal path: each wave rescores candidates j = w, w+4, ...
    for (int j = w; j < c; j += 4) {
      int mi = cand[(size_t)b * CAP + j];
      const float4* mv = (const float4*)(mem + (size_t)mi * DIM);
      float4 m0 = mv[lane * 2], m1 = mv[lane * 2 + 1];
      double m8[8] = {m0.x, m0.y, m0.z, m0.w, m1.x, m1.y, m1.z, m1.w};
      double dot = 0, mm = 0;
#pragma unroll
      for (int e = 0; e < 8; e++) { dot += q8[e] * m8[e]; mm += m8[e] * m8[e]; }
#pragma unroll
      for (int off = 32; off > 0; off >>= 1) {
        dot += __shfl_xor(dot, off);
        mm += __shfl_xor(mm, off);
      }
      if (lane == 0) {
        s_sims[j] = dot / (qnorm * fmax(sqrt(mm), 1e-8));
        s_cidx[j] = mi;
      }
    }
    n = c;
  } else {
    // fallback (cold, correctness-only): full scan, per-thread top-8, block merge
    double tv[8]; int tix[8];
#pragma unroll
    for (int r = 0; r < 8; r++) { tv[r] = -1e300; tix[r] = -1; }
    for (int row = tid; row < M_ROWS; row += 256) {
      const float4* mv = (const float4*)(mem + (size_t)row * DIM);
      double dot = 0, mm = 0;
      for (int e = 0; e < DIM / 4; e++) {
        float4 m4 = mv[e], qk = qv[e];
        dot += (double)m4.x * qk.x + (double)m4.y * qk.y + (double)m4.z * qk.z + (double)m4.w * qk.w;
        mm  += (double)m4.x * m4.x + (double)m4.y * m4.y + (double)m4.z * m4.z + (double)m4.w * m4.w;
      }
      double sim = dot / (qnorm * fmax(sqrt(mm), 1e-8));
      int am = 0;
#pragma unroll
      for (int r = 1; r < 8; r++) if (tv[r] < tv[am]) am = r;
      if (sim > tv[am]) { tv[am] = sim; tix[am] = row; }
    }
#pragma unroll
    for (int r = 0; r < 8; r++) { s_sims[tid * 8 + r] = tv[r]; s_cidx[tid * 8 + r] = tix[r]; }
    n = FB_N;
  }
  __syncthreads();

  // 8 rounds of block-wide argmax
  for (int r = 0; r < TOPK; r++) {
    double best = -1e300; int bj = -1;
    for (int j = tid; j < n; j += 256) {
      double v = s_sims[j];
      if (v > best) { best = v; bj = j; }
    }
#pragma unroll
    for (int off = 32; off > 0; off >>= 1) {
      double ov = __shfl_down(best, off);
      int oj = __shfl_down(bj, off);
      if (ov > best) { best = ov; bj = oj; }
    }
    if (lane == 0) { s_red[w] = best; s_redj[w] = bj; }
    __syncthreads();
    if (tid == 0) {
      double bb = s_red[0]; int jj = s_redj[0];
      for (int i = 1; i < 4; i++) if (s_red[i] > bb) { bb = s_red[i]; jj = s_redj[i]; }
      s_win[r] = s_cidx[jj];
      s_sims[jj] = -1e300;
    }
    __syncthreads();
  }

  // gather 8 winner rows, mean, write fp32 output
  float ax = 0.f, ay = 0.f;
#pragma unroll
  for (int r = 0; r < TOPK; r++) {
    const float2 v = *(const float2*)(mem + (size_t)s_win[r] * DIM + tid * 2);
    ax += v.x; ay += v.y;
  }
  float2 o; o.x = ax * 0.125f; o.y = ay * 0.125f;
  *(float2*)(out + (size_t)b * DIM + tid * 2) = o;
}

extern "C" void kernel_launch(void* const* d_in, const int* in_sizes, int n_in,
                              void* d_out, int out_size, void* d_ws, size_t ws_size,
                              hipStream_t stream) {
  (void)in_sizes; (void)n_in; (void)out_size; (void)ws_size;
  const float* q = (const float*)d_in[0];
  const float* mem = (const float*)d_in[1];
  float* out = (float*)d_out;

  char* ws = (char*)d_ws;
  u16* mn = (u16*)ws;                                        // 64 MB
  u16* qn = (u16*)(ws + (size_t)M_ROWS * DIM * 2);           // 4 MB
  int* count = (int*)(ws + (size_t)M_ROWS * DIM * 2 + (size_t)B_ROWS * DIM * 2);  // 16 KB
  int* cand = (int*)((char*)count + (size_t)B_ROWS * sizeof(int));                // 8 MB

  hipMemsetAsync(count, 0, B_ROWS * sizeof(int), stream);
  norm_kernel<<<M_ROWS / 4, 256, 0, stream>>>(mem, mn, M_ROWS);
  norm_kernel<<<B_ROWS / 4, 256, 0, stream>>>(q, qn, B_ROWS);
  gemm_select<<<(M_ROWS / 128) * (B_ROWS / 128), 256, 0, stream>>>(qn, mn, count, cand);
  topk_kernel<<<B_ROWS, 256, 0, stream>>>(q, mem, count, cand, out);
}